// Round 12
// baseline (210.989 us; speedup 1.0000x reference)
//
#include <hip/hip_runtime.h>
#include <math.h>

#define KCODES 2048
#define DIM 64
#define NROWS 65536          // 64*32*32
#define NELEM (NROWS * DIM)  // 4194304

// ws layout (bytes):
//   0      .. 8191    : hist[2048] (int)
//   8192   .. 16383   : c2[2048]  (float)   sum of squares per code (fixup uses)
//   16384  .. 24575   : c2s[2048] (float)   (c2+64)*16384  (packed-argmin bias)
//   24576  .. 24579   : sse (float)
//   24580  .. 24583   : ticket (int)        last-block-done counter
//   32768  .. 557055  : P — codebook as bf16 hi/lo of (-2*c), scaled-layout
//                       [64 tiles][8192B]: per tile, hi region [0,4096),
//                       lo region [4096,8192); byte(sn,g,e) = sn*128 + (g^(sn&7))*16 + e*2
//   557056 .. 1081343 : cbT[2048][64] f32 — codebook transpose for epilogue gather
#define WS_HIST 0
#define WS_C2   8192
#define WS_C2S  16384
#define WS_SSE  24576
#define WS_TKT  24580
#define WS_P    32768
#define WS_CBT  (32768 + 524288)

#define EPS_PK 33        // EPSM in 2^-14 units: 33*6.1e-5 = 2.01e-3

typedef float  floatx4 __attribute__((ext_vector_type(4)));
typedef short  short8  __attribute__((ext_vector_type(8)));

__device__ __forceinline__ unsigned short f2bf(float f) {
  union { float f; unsigned u; } a; a.f = f;
  unsigned r = (a.u + 0x7FFFu + ((a.u >> 16) & 1u)) >> 16;  // RNE, inputs finite
  return (unsigned short)r;
}
__device__ __forceinline__ float bf2f(unsigned short h) {
  union { unsigned u; float f; } a; a.u = ((unsigned)h) << 16;
  return a.f;
}

// Fused setup: P prepack (all threads); colnorm exact round-0 order (g==0);
// cbT transpose (g==1); hist zero (g==2); sse/ticket zero (g==3,code==0).
// 64 blocks x 256 = 2048 codes x 8 dim-groups.
__global__ void vq_setup(const float* __restrict__ cb, float* __restrict__ c2,
                         float* __restrict__ c2s, char* __restrict__ P,
                         float* __restrict__ cbT, int* __restrict__ hist,
                         float* __restrict__ sse, int* __restrict__ ticket) {
  int tid = blockIdx.x * 256 + threadIdx.x;
  int code = tid & (KCODES - 1);
  int g = tid >> 11;              // dim-group 0..7
  short8 hh, ll;
#pragma unroll
  for (int e = 0; e < 8; ++e) {
    float v = -2.0f * cb[(size_t)(g * 8 + e) * KCODES + code];
    unsigned short hb = f2bf(v);
    float lo = v - bf2f(hb);
    hh[e] = (short)hb;
    ll[e] = (short)f2bf(lo);
  }
  int tile = code >> 5;
  int sn = code & 31;
  int pb = g ^ (sn & 7);
  size_t base = (size_t)tile * 8192 + sn * 128 + pb * 16;
  *(short8*)(P + base) = hh;          // hi region
  *(short8*)(P + base + 4096) = ll;   // lo region

  if (g == 0) {
    // exact round-0 colnorm arithmetic order (scalar fmaf chain d=0..63)
    float s = 0.f;
#pragma unroll
    for (int d = 0; d < DIM; ++d) {
      float v = cb[(size_t)d * KCODES + code];
      s = fmaf(v, v, s);
    }
    c2[code] = s;
    c2s[code] = (s + 64.0f) * 16384.0f;
  } else if (g == 1) {
    // codebook transpose for the coalesced epilogue gather (exact copy)
    float* dst = cbT + (size_t)code * 64;
#pragma unroll
    for (int d4 = 0; d4 < 16; ++d4) {
      float4 w;
      w.x = cb[(size_t)(d4 * 4 + 0) * KCODES + code];
      w.y = cb[(size_t)(d4 * 4 + 1) * KCODES + code];
      w.z = cb[(size_t)(d4 * 4 + 2) * KCODES + code];
      w.w = cb[(size_t)(d4 * 4 + 3) * KCODES + code];
      *(float4*)(dst + d4 * 4) = w;
    }
  } else if (g == 2) {
    hist[code] = 0;
  } else if (g == 3 && code == 0) {
    *sse = 0.f;
    *ticket = 0;
  }
}

__device__ __forceinline__ void stage_tile(const char* P, char* lds,
                                           int tile, int w, int lane) {
  const char* gp = P + (size_t)tile * 8192 + w * 1024 + lane * 16;
  char* lp = lds + w * 1024 + lane * 16;
  __builtin_amdgcn_global_load_lds(
      (const __attribute__((address_space(1))) unsigned*)gp,
      (__attribute__((address_space(3))) unsigned*)lp, 16, 0, 0);
  __builtin_amdgcn_global_load_lds(
      (const __attribute__((address_space(1))) unsigned*)(gp + 4096),
      (__attribute__((address_space(3))) unsigned*)(lp + 4096), 16, 0, 0);
}

// Block = 256 thr = 4 waves; wave owns 32 rows (2 row-tiles); block = 128 rows.
// R11 structure (best: 106->100.5us): R9 K-loop (2 tiles/barrier, 32 exposures)
// + coalesced cbT float4 epilogue. ONE change vs R11: vq_final fused into the
// last block via ticket (3 -> 2 dispatches; saves final kernel + gap ~10-15us).
__global__ __launch_bounds__(256, 2) void vq_main(
    const float* __restrict__ inp, const float* __restrict__ cb,
    const float* __restrict__ c2, const float* __restrict__ c2s,
    const char* __restrict__ P, const float* __restrict__ cbT,
    int* __restrict__ hist, float* __restrict__ sse,
    int* __restrict__ ticket, float* __restrict__ out)
{
  __shared__ __align__(16) char Bstage[2][16384];
  __shared__ float s_c2s[KCODES];
  __shared__ int   s_k[128];
  __shared__ int   s_nflag;
  __shared__ int   s_frows[128];
  __shared__ float s_rd[256];
  __shared__ int   s_rk[256];
  __shared__ float s_red[4];
  __shared__ int   s_last;

  const int t    = threadIdx.x;
  const int lane = t & 63;
  const int wave = __builtin_amdgcn_readfirstlane(t >> 6);
  const int c    = lane & 15;   // MFMA col (code within 16-group)
  const int q    = lane >> 4;   // MFMA quad
  const int c7   = c & 7;
  const int rowbase = blockIdx.x * 128 + wave * 32;

  if (t == 0) s_nflag = 0;

  // c2s -> LDS table
#pragma unroll
  for (int i = 0; i < KCODES / 256; ++i) s_c2s[i * 256 + t] = c2s[i * 256 + t];

  // ---- A fragments: x rows scaled by 2^14, bf16 hi/lo, [rowtile r][kstep s] ----
  short8 Ah[2][2], Al[2][2];
#pragma unroll
  for (int r = 0; r < 2; ++r) {
#pragma unroll
    for (int s = 0; s < 2; ++s) {
      const float* px = inp + (size_t)(rowbase + r * 16 + c) * 64 + s * 32 + q * 8;
      float4 u0 = *(const float4*)px;
      float4 u1 = *(const float4*)(px + 4);
      float u[8] = {u0.x, u0.y, u0.z, u0.w, u1.x, u1.y, u1.z, u1.w};
      short8 hh, ll;
#pragma unroll
      for (int e = 0; e < 8; ++e) {
        float xs = u[e] * 16384.0f;           // exact pow2 scale
        unsigned short hb = f2bf(xs);
        float lo = xs - bf2f(hb);
        hh[e] = (short)hb;
        ll[e] = (short)f2bf(lo);
      }
      Ah[r][s] = hh; Al[r][s] = ll;
    }
  }

  // packed (dist<<11 | k) best / second-best per lane for 8 rows
  unsigned d1[8], d2[8];
#pragma unroll
  for (int i = 0; i < 8; ++i) { d1[i] = 0xFFFFFFFFu; d2[i] = 0xFFFFFFFFu; }

  // prologue: tiles 0,1 into buf0
  stage_tile(P, Bstage[0], 0, wave, lane);
  stage_tile(P, Bstage[0] + 8192, 1, wave, lane);
  __syncthreads();

  const floatx4 zero = {0.f, 0.f, 0.f, 0.f};

  // R0's compute body, byte-identical per j, reading tile base Bt
#define COMPUTE(Bt, j) do {                                                                 \
    float c2v0 = s_c2s[(j) * 32 + c];                                                       \
    float c2v1 = s_c2s[(j) * 32 + 16 + c];                                                  \
    _Pragma("unroll")                                                                       \
    for (int nt = 0; nt < 2; ++nt) {                                                        \
      const int rowi = nt * 16 + c;                                                         \
      const char* bp = (Bt) + rowi * 128;                                                   \
      short8 bh0 = *(const short8*)(bp + ((0 + q) ^ c7) * 16);                              \
      short8 bh1 = *(const short8*)(bp + ((4 + q) ^ c7) * 16);                              \
      short8 bl0 = *(const short8*)(bp + 4096 + ((0 + q) ^ c7) * 16);                       \
      short8 bl1 = *(const short8*)(bp + 4096 + ((4 + q) ^ c7) * 16);                       \
      const float c2v = nt ? c2v1 : c2v0;                                                   \
      const unsigned kcn = (j) * 32 + nt * 16 + c;                                          \
      _Pragma("unroll")                                                                     \
      for (int r = 0; r < 2; ++r) {                                                         \
        floatx4 acc = __builtin_amdgcn_mfma_f32_16x16x32_bf16(Al[r][1], bh1, zero, 0, 0, 0);\
        acc = __builtin_amdgcn_mfma_f32_16x16x32_bf16(Ah[r][1], bl1, acc, 0, 0, 0);         \
        acc = __builtin_amdgcn_mfma_f32_16x16x32_bf16(Al[r][0], bh0, acc, 0, 0, 0);         \
        acc = __builtin_amdgcn_mfma_f32_16x16x32_bf16(Ah[r][0], bl0, acc, 0, 0, 0);         \
        acc = __builtin_amdgcn_mfma_f32_16x16x32_bf16(Ah[r][1], bh1, acc, 0, 0, 0);         \
        acc = __builtin_amdgcn_mfma_f32_16x16x32_bf16(Ah[r][0], bh0, acc, 0, 0, 0);         \
        _Pragma("unroll")                                                                   \
        for (int reg = 0; reg < 4; ++reg) {                                                 \
          float dds = acc[reg] + c2v;                  /* S*(dist+64) > 0 */                \
          unsigned u = (((unsigned)dds) << 11) + kcn;  /* cvt + lshl_add */                 \
          const int i = r * 4 + reg;                                                        \
          d2[i] = min(d2[i], max(d1[i], u));                                                \
          d1[i] = min(d1[i], u);                                                            \
        }                                                                                   \
      }                                                                                     \
    }                                                                                       \
  } while (0)

#pragma unroll 2
  for (int jj = 0; jj < 32; ++jj) {
    const int buf = jj & 1;
    if (jj + 1 < 32) {
      stage_tile(P, Bstage[1 - buf], 2 * jj + 2, wave, lane);
      stage_tile(P, Bstage[1 - buf] + 8192, 2 * jj + 3, wave, lane);
    }
    COMPUTE(&Bstage[buf][0], 2 * jj);
    COMPUTE(&Bstage[buf][8192], 2 * jj + 1);
    __syncthreads();
  }

#undef COMPUTE

  // ---- cross-lane argmin reduce over the 16 code-columns (uint min) ----
#pragma unroll
  for (int i = 0; i < 8; ++i) {
    unsigned D1 = d1[i], D2 = d2[i];
#pragma unroll
    for (int off = 1; off < 16; off <<= 1) {
      unsigned o1 = (unsigned)__shfl_xor((int)D1, off, 64);
      unsigned o2 = (unsigned)__shfl_xor((int)D2, off, 64);
      D2 = min(min(D2, o2), max(D1, o1));
      D1 = min(D1, o1);
    }
    if (c == 0) {
      int lrow = wave * 32 + (i >> 2) * 16 + q * 4 + (i & 3);
      s_k[lrow] = (int)(D1 & 2047u);
      if ((int)((D2 >> 11) - (D1 >> 11)) < EPS_PK) {
        int idx = atomicAdd(&s_nflag, 1);
        s_frows[idx] = lrow;
      }
    }
  }
  __syncthreads();

  // ---- exact fp32 fixup for near-tie rows (round-0 arithmetic, proven) ----
  const int nf = s_nflag;
  for (int f = 0; f < nf; ++f) {
    const int lrow = s_frows[f];
    const float* xr = inp + (size_t)(blockIdx.x * 128 + lrow) * 64;
    float xs[64];
    float x2 = 0.f;
#pragma unroll
    for (int i = 0; i < 16; ++i) {
      float4 v = *(const float4*)(xr + i * 4);
      xs[4 * i + 0] = v.x; xs[4 * i + 1] = v.y; xs[4 * i + 2] = v.z; xs[4 * i + 3] = v.w;
      x2 = fmaf(v.x, v.x, x2); x2 = fmaf(v.y, v.y, x2);
      x2 = fmaf(v.z, v.z, x2); x2 = fmaf(v.w, v.w, x2);
    }
    float dot[8];
#pragma unroll
    for (int cc = 0; cc < 8; ++cc) dot[cc] = 0.f;
    const float* cp = cb + t * 8;
#pragma unroll 4
    for (int d = 0; d < 64; ++d) {
      float xd = xs[d];
#pragma unroll
      for (int cc = 0; cc < 8; ++cc)
        dot[cc] = fmaf(xd, cp[(size_t)d * KCODES + cc], dot[cc]);
    }
    float bd = INFINITY; int bk = 0;
#pragma unroll
    for (int cc = 0; cc < 8; ++cc) {
      float dd = (x2 - 2.0f * dot[cc]) + c2[t * 8 + cc];
      if (dd < bd) { bd = dd; bk = t * 8 + cc; }
    }
    s_rd[t] = bd; s_rk[t] = bk;
    __syncthreads();
    for (int s = 128; s >= 1; s >>= 1) {
      if (t < s) {
        if (s_rd[t + s] < s_rd[t]) { s_rd[t] = s_rd[t + s]; s_rk[t] = s_rk[t + s]; }
      }
      __syncthreads();
    }
    if (t == 0) s_k[lrow] = s_rk[0];
    __syncthreads();
  }

  if (t < 128) atomicAdd(&hist[s_k[t]], 1);

  // ---- epilogue: coalesced float4 STE write + SSE, q gathered from cbT ----
  const float* xb = inp + (size_t)blockIdx.x * (128 * 64);
  float* ob = out + (size_t)blockIdx.x * (128 * 64);
  float serr = 0.f;
#pragma unroll
  for (int i = 0; i < 8; ++i) {
    const int idx = i * 1024 + t * 4;
    const int myk = s_k[idx >> 6];
    const float4 xv = *(const float4*)(xb + idx);
    const float4 qv = *(const float4*)(cbT + (size_t)myk * 64 + (idx & 63));
    float4 ov;
    float e0 = qv.x - xv.x; serr = fmaf(e0, e0, serr); ov.x = xv.x + e0;
    float e1 = qv.y - xv.y; serr = fmaf(e1, e1, serr); ov.y = xv.y + e1;
    float e2 = qv.z - xv.z; serr = fmaf(e2, e2, serr); ov.z = xv.z + e2;
    float e3 = qv.w - xv.w; serr = fmaf(e3, e3, serr); ov.w = xv.w + e3;
    *(float4*)(ob + idx) = ov;
  }
#pragma unroll
  for (int off = 32; off > 0; off >>= 1) serr += __shfl_down(serr, off, 64);
  if (lane == 0) s_red[wave] = serr;
  __syncthreads();
  if (t == 0) atomicAdd(sse, s_red[0] + s_red[1] + s_red[2] + s_red[3]);

  // ---- fused final: last block computes perplexity + losses (R1-R7 pattern) ----
  __threadfence();
  __syncthreads();
  if (t == 0) s_last = (atomicAdd(ticket, 1) == (int)gridDim.x - 1) ? 1 : 0;
  __syncthreads();
  if (s_last) {
    float s = 0.f;
    for (int k = t; k < KCODES; k += 256) {
      int h = atomicAdd(&hist[k], 0);           // device-coherent read
      float p = (float)h * (1.0f / NROWS);
      s += p * logf(p + 1e-10f);
    }
#pragma unroll
    for (int off = 32; off > 0; off >>= 1) s += __shfl_down(s, off, 64);
    if (lane == 0) s_red[wave] = s;
    __syncthreads();
    if (t == 0) {
      float tot = s_red[0] + s_red[1] + s_red[2] + s_red[3];
      float sv = atomicAdd(sse, 0.0f);          // device-coherent read
      out[NELEM] = expf(-tot);                  // perplexity
      float cl = sv * (1.0f / NELEM);
      out[NELEM + 1] = cl;                      // codebook_loss
      out[NELEM + 2] = 0.25f * cl;              // commitment_loss
    }
  }
}

extern "C" void kernel_launch(void* const* d_in, const int* in_sizes, int n_in,
                              void* d_out, int out_size, void* d_ws, size_t ws_size,
                              hipStream_t stream) {
  const float* inp = (const float*)d_in[0];
  const float* cb  = (const float*)d_in[1];
  float* out = (float*)d_out;
  char* ws = (char*)d_ws;
  int*   hist = (int*)(ws + WS_HIST);
  float* c2   = (float*)(ws + WS_C2);
  float* c2s  = (float*)(ws + WS_C2S);
  float* sse  = (float*)(ws + WS_SSE);
  int*   tkt  = (int*)(ws + WS_TKT);
  char*  P    = ws + WS_P;
  float* cbT  = (float*)(ws + WS_CBT);

  vq_setup<<<KCODES * 8 / 256, 256, 0, stream>>>(cb, c2, c2s, P, cbT, hist, sse, tkt);
  vq_main<<<NROWS / 128, 256, 0, stream>>>(inp, cb, c2, c2s, P, cbT, hist, sse, tkt, out);
}

// Round 13
// 162.872 us; speedup vs baseline: 1.2954x; 1.2954x over previous
//
#include <hip/hip_runtime.h>
#include <math.h>

#define KCODES 2048
#define DIM 64
#define NROWS 65536          // 64*32*32
#define NELEM (NROWS * DIM)  // 4194304

// ws layout (bytes):
//   0      .. 8191    : hist[2048] (int)
//   8192   .. 16383   : c2[2048]  (float)   sum of squares per code (fixup uses)
//   16384  .. 24575   : c2s[2048] (float)   (c2+64)*16384  (packed-argmin bias)
//   24576  .. 24579   : sse (float)
//   32768  .. 557055  : P — codebook as bf16 hi/lo of (-2*c), scaled-layout
//                       [64 tiles][8192B]: per tile, hi region [0,4096),
//                       lo region [4096,8192); byte(sn,g,e) = sn*128 + (g^(sn&7))*16 + e*2
//   557056 .. 1081343 : cbT[2048][64] f32 — codebook transpose for epilogue gather
#define WS_HIST 0
#define WS_C2   8192
#define WS_C2S  16384
#define WS_SSE  24576
#define WS_P    32768
#define WS_CBT  (32768 + 524288)

#define EPS_PK 33        // EPSM in 2^-14 units: 33*6.1e-5 = 2.01e-3

typedef float  floatx4 __attribute__((ext_vector_type(4)));
typedef short  short8  __attribute__((ext_vector_type(8)));

__device__ __forceinline__ unsigned short f2bf(float f) {
  union { float f; unsigned u; } a; a.f = f;
  unsigned r = (a.u + 0x7FFFu + ((a.u >> 16) & 1u)) >> 16;  // RNE, inputs finite
  return (unsigned short)r;
}
__device__ __forceinline__ float bf2f(unsigned short h) {
  union { unsigned u; float f; } a; a.u = ((unsigned)h) << 16;
  return a.f;
}

// Fused setup: P prepack (all threads); colnorm exact round-0 order (g==0);
// cbT transpose (g==1); hist zero (g==2); sse zero (g==3,code==0).
// 64 blocks x 256 = 2048 codes x 8 dim-groups.
__global__ void vq_setup(const float* __restrict__ cb, float* __restrict__ c2,
                         float* __restrict__ c2s, char* __restrict__ P,
                         float* __restrict__ cbT, int* __restrict__ hist,
                         float* __restrict__ sse) {
  int tid = blockIdx.x * 256 + threadIdx.x;
  int code = tid & (KCODES - 1);
  int g = tid >> 11;              // dim-group 0..7
  short8 hh, ll;
#pragma unroll
  for (int e = 0; e < 8; ++e) {
    float v = -2.0f * cb[(size_t)(g * 8 + e) * KCODES + code];
    unsigned short hb = f2bf(v);
    float lo = v - bf2f(hb);
    hh[e] = (short)hb;
    ll[e] = (short)f2bf(lo);
  }
  int tile = code >> 5;
  int sn = code & 31;
  int pb = g ^ (sn & 7);
  size_t base = (size_t)tile * 8192 + sn * 128 + pb * 16;
  *(short8*)(P + base) = hh;          // hi region
  *(short8*)(P + base + 4096) = ll;   // lo region

  if (g == 0) {
    // exact round-0 colnorm arithmetic order (scalar fmaf chain d=0..63)
    float s = 0.f;
#pragma unroll
    for (int d = 0; d < DIM; ++d) {
      float v = cb[(size_t)d * KCODES + code];
      s = fmaf(v, v, s);
    }
    c2[code] = s;
    c2s[code] = (s + 64.0f) * 16384.0f;
  } else if (g == 1) {
    // codebook transpose for the coalesced epilogue gather (exact copy)
    float* dst = cbT + (size_t)code * 64;
#pragma unroll
    for (int d4 = 0; d4 < 16; ++d4) {
      float4 w;
      w.x = cb[(size_t)(d4 * 4 + 0) * KCODES + code];
      w.y = cb[(size_t)(d4 * 4 + 1) * KCODES + code];
      w.z = cb[(size_t)(d4 * 4 + 2) * KCODES + code];
      w.w = cb[(size_t)(d4 * 4 + 3) * KCODES + code];
      *(float4*)(dst + d4 * 4) = w;
    }
  } else if (g == 2) {
    hist[code] = 0;
  } else if (g == 3 && code == 0) {
    *sse = 0.f;
  }
}

__device__ __forceinline__ void stage_tile(const char* P, char* lds,
                                           int tile, int w, int lane) {
  const char* gp = P + (size_t)tile * 8192 + w * 1024 + lane * 16;
  char* lp = lds + w * 1024 + lane * 16;
  __builtin_amdgcn_global_load_lds(
      (const __attribute__((address_space(1))) unsigned*)gp,
      (__attribute__((address_space(3))) unsigned*)lp, 16, 0, 0);
  __builtin_amdgcn_global_load_lds(
      (const __attribute__((address_space(1))) unsigned*)(gp + 4096),
      (__attribute__((address_space(3))) unsigned*)(lp + 4096), 16, 0, 0);
}

// Block = 256 thr = 4 waves; wave owns 32 rows (2 row-tiles); block = 128 rows.
// R11 = measured optimum of every axis explored over 12 rounds:
//  - K-loop: 2 tiles/barrier, 2x16KB dbuf, 32 latency exposures
//    (64exp=117us, 32exp=106us, 16exp=123us — sharp minimum)
//  - staging: global_load_lds + per-pair __syncthreads (counted-vmcnt,
//    no-barrier, stagger, chunked all regressed)
//  - epilogue: coalesced float4 + cbT gather (-5.5us vs scalar)
//  - separate vq_final dispatch (fusing it in costs +47us: threadfence/L2)
__global__ __launch_bounds__(256, 2) void vq_main(
    const float* __restrict__ inp, const float* __restrict__ cb,
    const float* __restrict__ c2, const float* __restrict__ c2s,
    const char* __restrict__ P, const float* __restrict__ cbT,
    int* __restrict__ hist, float* __restrict__ sse, float* __restrict__ out)
{
  __shared__ __align__(16) char Bstage[2][16384];
  __shared__ float s_c2s[KCODES];
  __shared__ int   s_k[128];
  __shared__ int   s_nflag;
  __shared__ int   s_frows[128];
  __shared__ float s_rd[256];
  __shared__ int   s_rk[256];
  __shared__ float s_red[4];

  const int t    = threadIdx.x;
  const int lane = t & 63;
  const int wave = __builtin_amdgcn_readfirstlane(t >> 6);
  const int c    = lane & 15;   // MFMA col (code within 16-group)
  const int q    = lane >> 4;   // MFMA quad
  const int c7   = c & 7;
  const int rowbase = blockIdx.x * 128 + wave * 32;

  if (t == 0) s_nflag = 0;

  // c2s -> LDS table
#pragma unroll
  for (int i = 0; i < KCODES / 256; ++i) s_c2s[i * 256 + t] = c2s[i * 256 + t];

  // ---- A fragments: x rows scaled by 2^14, bf16 hi/lo, [rowtile r][kstep s] ----
  short8 Ah[2][2], Al[2][2];
#pragma unroll
  for (int r = 0; r < 2; ++r) {
#pragma unroll
    for (int s = 0; s < 2; ++s) {
      const float* px = inp + (size_t)(rowbase + r * 16 + c) * 64 + s * 32 + q * 8;
      float4 u0 = *(const float4*)px;
      float4 u1 = *(const float4*)(px + 4);
      float u[8] = {u0.x, u0.y, u0.z, u0.w, u1.x, u1.y, u1.z, u1.w};
      short8 hh, ll;
#pragma unroll
      for (int e = 0; e < 8; ++e) {
        float xs = u[e] * 16384.0f;           // exact pow2 scale
        unsigned short hb = f2bf(xs);
        float lo = xs - bf2f(hb);
        hh[e] = (short)hb;
        ll[e] = (short)f2bf(lo);
      }
      Ah[r][s] = hh; Al[r][s] = ll;
    }
  }

  // packed (dist<<11 | k) best / second-best per lane for 8 rows
  unsigned d1[8], d2[8];
#pragma unroll
  for (int i = 0; i < 8; ++i) { d1[i] = 0xFFFFFFFFu; d2[i] = 0xFFFFFFFFu; }

  // prologue: tiles 0,1 into buf0
  stage_tile(P, Bstage[0], 0, wave, lane);
  stage_tile(P, Bstage[0] + 8192, 1, wave, lane);
  __syncthreads();

  const floatx4 zero = {0.f, 0.f, 0.f, 0.f};

  // R0's compute body, byte-identical per j, reading tile base Bt
#define COMPUTE(Bt, j) do {                                                                 \
    float c2v0 = s_c2s[(j) * 32 + c];                                                       \
    float c2v1 = s_c2s[(j) * 32 + 16 + c];                                                  \
    _Pragma("unroll")                                                                       \
    for (int nt = 0; nt < 2; ++nt) {                                                        \
      const int rowi = nt * 16 + c;                                                         \
      const char* bp = (Bt) + rowi * 128;                                                   \
      short8 bh0 = *(const short8*)(bp + ((0 + q) ^ c7) * 16);                              \
      short8 bh1 = *(const short8*)(bp + ((4 + q) ^ c7) * 16);                              \
      short8 bl0 = *(const short8*)(bp + 4096 + ((0 + q) ^ c7) * 16);                       \
      short8 bl1 = *(const short8*)(bp + 4096 + ((4 + q) ^ c7) * 16);                       \
      const float c2v = nt ? c2v1 : c2v0;                                                   \
      const unsigned kcn = (j) * 32 + nt * 16 + c;                                          \
      _Pragma("unroll")                                                                     \
      for (int r = 0; r < 2; ++r) {                                                         \
        floatx4 acc = __builtin_amdgcn_mfma_f32_16x16x32_bf16(Al[r][1], bh1, zero, 0, 0, 0);\
        acc = __builtin_amdgcn_mfma_f32_16x16x32_bf16(Ah[r][1], bl1, acc, 0, 0, 0);         \
        acc = __builtin_amdgcn_mfma_f32_16x16x32_bf16(Al[r][0], bh0, acc, 0, 0, 0);         \
        acc = __builtin_amdgcn_mfma_f32_16x16x32_bf16(Ah[r][0], bl0, acc, 0, 0, 0);         \
        acc = __builtin_amdgcn_mfma_f32_16x16x32_bf16(Ah[r][1], bh1, acc, 0, 0, 0);         \
        acc = __builtin_amdgcn_mfma_f32_16x16x32_bf16(Ah[r][0], bh0, acc, 0, 0, 0);         \
        _Pragma("unroll")                                                                   \
        for (int reg = 0; reg < 4; ++reg) {                                                 \
          float dds = acc[reg] + c2v;                  /* S*(dist+64) > 0 */                \
          unsigned u = (((unsigned)dds) << 11) + kcn;  /* cvt + lshl_add */                 \
          const int i = r * 4 + reg;                                                        \
          d2[i] = min(d2[i], max(d1[i], u));                                                \
          d1[i] = min(d1[i], u);                                                            \
        }                                                                                   \
      }                                                                                     \
    }                                                                                       \
  } while (0)

#pragma unroll 2
  for (int jj = 0; jj < 32; ++jj) {
    const int buf = jj & 1;
    if (jj + 1 < 32) {
      stage_tile(P, Bstage[1 - buf], 2 * jj + 2, wave, lane);
      stage_tile(P, Bstage[1 - buf] + 8192, 2 * jj + 3, wave, lane);
    }
    COMPUTE(&Bstage[buf][0], 2 * jj);
    COMPUTE(&Bstage[buf][8192], 2 * jj + 1);
    __syncthreads();
  }

#undef COMPUTE

  // ---- cross-lane argmin reduce over the 16 code-columns (uint min) ----
#pragma unroll
  for (int i = 0; i < 8; ++i) {
    unsigned D1 = d1[i], D2 = d2[i];
#pragma unroll
    for (int off = 1; off < 16; off <<= 1) {
      unsigned o1 = (unsigned)__shfl_xor((int)D1, off, 64);
      unsigned o2 = (unsigned)__shfl_xor((int)D2, off, 64);
      D2 = min(min(D2, o2), max(D1, o1));
      D1 = min(D1, o1);
    }
    if (c == 0) {
      int lrow = wave * 32 + (i >> 2) * 16 + q * 4 + (i & 3);
      s_k[lrow] = (int)(D1 & 2047u);
      if ((int)((D2 >> 11) - (D1 >> 11)) < EPS_PK) {
        int idx = atomicAdd(&s_nflag, 1);
        s_frows[idx] = lrow;
      }
    }
  }
  __syncthreads();

  // ---- exact fp32 fixup for near-tie rows (round-0 arithmetic, proven) ----
  const int nf = s_nflag;
  for (int f = 0; f < nf; ++f) {
    const int lrow = s_frows[f];
    const float* xr = inp + (size_t)(blockIdx.x * 128 + lrow) * 64;
    float xs[64];
    float x2 = 0.f;
#pragma unroll
    for (int i = 0; i < 16; ++i) {
      float4 v = *(const float4*)(xr + i * 4);
      xs[4 * i + 0] = v.x; xs[4 * i + 1] = v.y; xs[4 * i + 2] = v.z; xs[4 * i + 3] = v.w;
      x2 = fmaf(v.x, v.x, x2); x2 = fmaf(v.y, v.y, x2);
      x2 = fmaf(v.z, v.z, x2); x2 = fmaf(v.w, v.w, x2);
    }
    float dot[8];
#pragma unroll
    for (int cc = 0; cc < 8; ++cc) dot[cc] = 0.f;
    const float* cp = cb + t * 8;
#pragma unroll 4
    for (int d = 0; d < 64; ++d) {
      float xd = xs[d];
#pragma unroll
      for (int cc = 0; cc < 8; ++cc)
        dot[cc] = fmaf(xd, cp[(size_t)d * KCODES + cc], dot[cc]);
    }
    float bd = INFINITY; int bk = 0;
#pragma unroll
    for (int cc = 0; cc < 8; ++cc) {
      float dd = (x2 - 2.0f * dot[cc]) + c2[t * 8 + cc];
      if (dd < bd) { bd = dd; bk = t * 8 + cc; }
    }
    s_rd[t] = bd; s_rk[t] = bk;
    __syncthreads();
    for (int s = 128; s >= 1; s >>= 1) {
      if (t < s) {
        if (s_rd[t + s] < s_rd[t]) { s_rd[t] = s_rd[t + s]; s_rk[t] = s_rk[t + s]; }
      }
      __syncthreads();
    }
    if (t == 0) s_k[lrow] = s_rk[0];
    __syncthreads();
  }

  if (t < 128) atomicAdd(&hist[s_k[t]], 1);

  // ---- epilogue: coalesced float4 STE write + SSE, q gathered from cbT ----
  const float* xb = inp + (size_t)blockIdx.x * (128 * 64);
  float* ob = out + (size_t)blockIdx.x * (128 * 64);
  float serr = 0.f;
#pragma unroll
  for (int i = 0; i < 8; ++i) {
    const int idx = i * 1024 + t * 4;
    const int myk = s_k[idx >> 6];
    const float4 xv = *(const float4*)(xb + idx);
    const float4 qv = *(const float4*)(cbT + (size_t)myk * 64 + (idx & 63));
    float4 ov;
    float e0 = qv.x - xv.x; serr = fmaf(e0, e0, serr); ov.x = xv.x + e0;
    float e1 = qv.y - xv.y; serr = fmaf(e1, e1, serr); ov.y = xv.y + e1;
    float e2 = qv.z - xv.z; serr = fmaf(e2, e2, serr); ov.z = xv.z + e2;
    float e3 = qv.w - xv.w; serr = fmaf(e3, e3, serr); ov.w = xv.w + e3;
    *(float4*)(ob + idx) = ov;
  }
#pragma unroll
  for (int off = 32; off > 0; off >>= 1) serr += __shfl_down(serr, off, 64);
  if (lane == 0) s_red[wave] = serr;
  __syncthreads();
  if (t == 0) atomicAdd(sse, s_red[0] + s_red[1] + s_red[2] + s_red[3]);
}

__global__ void vq_final(const int* __restrict__ hist,
                         const float* __restrict__ sse,
                         float* __restrict__ out) {
  __shared__ float s_red[4];
  const int t = threadIdx.x;
  float s = 0.f;
  for (int k = t; k < KCODES; k += 256) {
    float p = (float)hist[k] * (1.0f / NROWS);
    s += p * logf(p + 1e-10f);
  }
#pragma unroll
  for (int off = 32; off > 0; off >>= 1) s += __shfl_down(s, off, 64);
  if ((t & 63) == 0) s_red[t >> 6] = s;
  __syncthreads();
  if (t == 0) {
    float tot = s_red[0] + s_red[1] + s_red[2] + s_red[3];
    out[NELEM] = expf(-tot);                 // perplexity
    float cl = *sse * (1.0f / NELEM);
    out[NELEM + 1] = cl;                     // codebook_loss
    out[NELEM + 2] = 0.25f * cl;             // commitment_loss
  }
}

extern "C" void kernel_launch(void* const* d_in, const int* in_sizes, int n_in,
                              void* d_out, int out_size, void* d_ws, size_t ws_size,
                              hipStream_t stream) {
  const float* inp = (const float*)d_in[0];
  const float* cb  = (const float*)d_in[1];
  float* out = (float*)d_out;
  char* ws = (char*)d_ws;
  int*   hist = (int*)(ws + WS_HIST);
  float* c2   = (float*)(ws + WS_C2);
  float* c2s  = (float*)(ws + WS_C2S);
  float* sse  = (float*)(ws + WS_SSE);
  char*  P    = ws + WS_P;
  float* cbT  = (float*)(ws + WS_CBT);

  vq_setup<<<KCODES * 8 / 256, 256, 0, stream>>>(cb, c2, c2s, P, cbT, hist, sse);
  vq_main<<<NROWS / 128, 256, 0, stream>>>(inp, cb, c2, c2s, P, cbT, hist, sse, out);
  vq_final<<<1, 256, 0, stream>>>(hist, sse, out);
}

// Round 14
// 162.814 us; speedup vs baseline: 1.2959x; 1.0004x over previous
//
#include <hip/hip_runtime.h>
#include <math.h>

#define KCODES 2048
#define DIM 64
#define NROWS 65536          // 64*32*32
#define NELEM (NROWS * DIM)  // 4194304

// ws layout (bytes):
//   0      .. 8191    : hist[2048] (int)
//   8192   .. 16383   : c2[2048]  (float)   sum of squares per code (fixup uses)
//   16384  .. 24575   : c2s[2048] (float)   (c2+64)*16384  (packed-argmin bias)
//   24576  .. 24579   : sse (float)
//   32768  .. 557055  : P — codebook as bf16 hi/lo of (-2*c), scaled-layout
//                       [64 tiles][8192B]: per tile, hi region [0,4096),
//                       lo region [4096,8192); byte(sn,g,e) = sn*128 + (g^(sn&7))*16 + e*2
//   557056 .. 1081343 : cbT[2048][64] f32 — codebook transpose for epilogue gather
#define WS_HIST 0
#define WS_C2   8192
#define WS_C2S  16384
#define WS_SSE  24576
#define WS_P    32768
#define WS_CBT  (32768 + 524288)

#define EPS_PK 33        // EPSM in 2^-14 units: 33*6.1e-5 = 2.01e-3

typedef float  floatx4 __attribute__((ext_vector_type(4)));
typedef short  short8  __attribute__((ext_vector_type(8)));

__device__ __forceinline__ unsigned short f2bf(float f) {
  union { float f; unsigned u; } a; a.f = f;
  unsigned r = (a.u + 0x7FFFu + ((a.u >> 16) & 1u)) >> 16;  // RNE, inputs finite
  return (unsigned short)r;
}
__device__ __forceinline__ float bf2f(unsigned short h) {
  union { unsigned u; float f; } a; a.u = ((unsigned)h) << 16;
  return a.f;
}

// Fused setup: P prepack (all threads); colnorm exact round-0 order (g==0);
// cbT transpose (g==1); hist zero (g==2); sse zero (g==3,code==0).
// R14: SAME 16384 threads / SAME tid mapping / bit-identical work, but
// 256 blocks x 64 thr (was 64 x 256) -> all 256 CUs active (was 64).
__global__ void vq_setup(const float* __restrict__ cb, float* __restrict__ c2,
                         float* __restrict__ c2s, char* __restrict__ P,
                         float* __restrict__ cbT, int* __restrict__ hist,
                         float* __restrict__ sse) {
  int tid = blockIdx.x * 64 + threadIdx.x;
  int code = tid & (KCODES - 1);
  int g = tid >> 11;              // dim-group 0..7
  short8 hh, ll;
#pragma unroll
  for (int e = 0; e < 8; ++e) {
    float v = -2.0f * cb[(size_t)(g * 8 + e) * KCODES + code];
    unsigned short hb = f2bf(v);
    float lo = v - bf2f(hb);
    hh[e] = (short)hb;
    ll[e] = (short)f2bf(lo);
  }
  int tile = code >> 5;
  int sn = code & 31;
  int pb = g ^ (sn & 7);
  size_t base = (size_t)tile * 8192 + sn * 128 + pb * 16;
  *(short8*)(P + base) = hh;          // hi region
  *(short8*)(P + base + 4096) = ll;   // lo region

  if (g == 0) {
    // exact round-0 colnorm arithmetic order (scalar fmaf chain d=0..63)
    float s = 0.f;
#pragma unroll
    for (int d = 0; d < DIM; ++d) {
      float v = cb[(size_t)d * KCODES + code];
      s = fmaf(v, v, s);
    }
    c2[code] = s;
    c2s[code] = (s + 64.0f) * 16384.0f;
  } else if (g == 1) {
    // codebook transpose for the coalesced epilogue gather (exact copy)
    float* dst = cbT + (size_t)code * 64;
#pragma unroll
    for (int d4 = 0; d4 < 16; ++d4) {
      float4 w;
      w.x = cb[(size_t)(d4 * 4 + 0) * KCODES + code];
      w.y = cb[(size_t)(d4 * 4 + 1) * KCODES + code];
      w.z = cb[(size_t)(d4 * 4 + 2) * KCODES + code];
      w.w = cb[(size_t)(d4 * 4 + 3) * KCODES + code];
      *(float4*)(dst + d4 * 4) = w;
    }
  } else if (g == 2) {
    hist[code] = 0;
  } else if (g == 3 && code == 0) {
    *sse = 0.f;
  }
}

__device__ __forceinline__ void stage_tile(const char* P, char* lds,
                                           int tile, int w, int lane) {
  const char* gp = P + (size_t)tile * 8192 + w * 1024 + lane * 16;
  char* lp = lds + w * 1024 + lane * 16;
  __builtin_amdgcn_global_load_lds(
      (const __attribute__((address_space(1))) unsigned*)gp,
      (__attribute__((address_space(3))) unsigned*)lp, 16, 0, 0);
  __builtin_amdgcn_global_load_lds(
      (const __attribute__((address_space(1))) unsigned*)(gp + 4096),
      (__attribute__((address_space(3))) unsigned*)(lp + 4096), 16, 0, 0);
}

// Block = 256 thr = 4 waves; wave owns 32 rows (2 row-tiles); block = 128 rows.
// R11/R13 = measured optimum of every axis explored over 13 rounds:
//  - K-loop: 2 tiles/barrier, 2x16KB dbuf, 32 latency exposures
//    (64exp=117us, 32exp=106us, 16exp=123us — sharp minimum)
//  - staging: global_load_lds + per-pair __syncthreads (counted-vmcnt,
//    no-barrier, stagger, chunked all regressed)
//  - epilogue: coalesced float4 + cbT gather (-5.5us vs scalar)
//  - separate vq_final dispatch (fusing it in costs +47us: threadfence/L2)
__global__ __launch_bounds__(256, 2) void vq_main(
    const float* __restrict__ inp, const float* __restrict__ cb,
    const float* __restrict__ c2, const float* __restrict__ c2s,
    const char* __restrict__ P, const float* __restrict__ cbT,
    int* __restrict__ hist, float* __restrict__ sse, float* __restrict__ out)
{
  __shared__ __align__(16) char Bstage[2][16384];
  __shared__ float s_c2s[KCODES];
  __shared__ int   s_k[128];
  __shared__ int   s_nflag;
  __shared__ int   s_frows[128];
  __shared__ float s_rd[256];
  __shared__ int   s_rk[256];
  __shared__ float s_red[4];

  const int t    = threadIdx.x;
  const int lane = t & 63;
  const int wave = __builtin_amdgcn_readfirstlane(t >> 6);
  const int c    = lane & 15;   // MFMA col (code within 16-group)
  const int q    = lane >> 4;   // MFMA quad
  const int c7   = c & 7;
  const int rowbase = blockIdx.x * 128 + wave * 32;

  if (t == 0) s_nflag = 0;

  // c2s -> LDS table
#pragma unroll
  for (int i = 0; i < KCODES / 256; ++i) s_c2s[i * 256 + t] = c2s[i * 256 + t];

  // ---- A fragments: x rows scaled by 2^14, bf16 hi/lo, [rowtile r][kstep s] ----
  short8 Ah[2][2], Al[2][2];
#pragma unroll
  for (int r = 0; r < 2; ++r) {
#pragma unroll
    for (int s = 0; s < 2; ++s) {
      const float* px = inp + (size_t)(rowbase + r * 16 + c) * 64 + s * 32 + q * 8;
      float4 u0 = *(const float4*)px;
      float4 u1 = *(const float4*)(px + 4);
      float u[8] = {u0.x, u0.y, u0.z, u0.w, u1.x, u1.y, u1.z, u1.w};
      short8 hh, ll;
#pragma unroll
      for (int e = 0; e < 8; ++e) {
        float xs = u[e] * 16384.0f;           // exact pow2 scale
        unsigned short hb = f2bf(xs);
        float lo = xs - bf2f(hb);
        hh[e] = (short)hb;
        ll[e] = (short)f2bf(lo);
      }
      Ah[r][s] = hh; Al[r][s] = ll;
    }
  }

  // packed (dist<<11 | k) best / second-best per lane for 8 rows
  unsigned d1[8], d2[8];
#pragma unroll
  for (int i = 0; i < 8; ++i) { d1[i] = 0xFFFFFFFFu; d2[i] = 0xFFFFFFFFu; }

  // prologue: tiles 0,1 into buf0
  stage_tile(P, Bstage[0], 0, wave, lane);
  stage_tile(P, Bstage[0] + 8192, 1, wave, lane);
  __syncthreads();

  const floatx4 zero = {0.f, 0.f, 0.f, 0.f};

  // R0's compute body, byte-identical per j, reading tile base Bt
#define COMPUTE(Bt, j) do {                                                                 \
    float c2v0 = s_c2s[(j) * 32 + c];                                                       \
    float c2v1 = s_c2s[(j) * 32 + 16 + c];                                                  \
    _Pragma("unroll")                                                                       \
    for (int nt = 0; nt < 2; ++nt) {                                                        \
      const int rowi = nt * 16 + c;                                                         \
      const char* bp = (Bt) + rowi * 128;                                                   \
      short8 bh0 = *(const short8*)(bp + ((0 + q) ^ c7) * 16);                              \
      short8 bh1 = *(const short8*)(bp + ((4 + q) ^ c7) * 16);                              \
      short8 bl0 = *(const short8*)(bp + 4096 + ((0 + q) ^ c7) * 16);                       \
      short8 bl1 = *(const short8*)(bp + 4096 + ((4 + q) ^ c7) * 16);                       \
      const float c2v = nt ? c2v1 : c2v0;                                                   \
      const unsigned kcn = (j) * 32 + nt * 16 + c;                                          \
      _Pragma("unroll")                                                                     \
      for (int r = 0; r < 2; ++r) {                                                         \
        floatx4 acc = __builtin_amdgcn_mfma_f32_16x16x32_bf16(Al[r][1], bh1, zero, 0, 0, 0);\
        acc = __builtin_amdgcn_mfma_f32_16x16x32_bf16(Ah[r][1], bl1, acc, 0, 0, 0);         \
        acc = __builtin_amdgcn_mfma_f32_16x16x32_bf16(Al[r][0], bh0, acc, 0, 0, 0);         \
        acc = __builtin_amdgcn_mfma_f32_16x16x32_bf16(Ah[r][0], bl0, acc, 0, 0, 0);         \
        acc = __builtin_amdgcn_mfma_f32_16x16x32_bf16(Ah[r][1], bh1, acc, 0, 0, 0);         \
        acc = __builtin_amdgcn_mfma_f32_16x16x32_bf16(Ah[r][0], bh0, acc, 0, 0, 0);         \
        _Pragma("unroll")                                                                   \
        for (int reg = 0; reg < 4; ++reg) {                                                 \
          float dds = acc[reg] + c2v;                  /* S*(dist+64) > 0 */                \
          unsigned u = (((unsigned)dds) << 11) + kcn;  /* cvt + lshl_add */                 \
          const int i = r * 4 + reg;                                                        \
          d2[i] = min(d2[i], max(d1[i], u));                                                \
          d1[i] = min(d1[i], u);                                                            \
        }                                                                                   \
      }                                                                                     \
    }                                                                                       \
  } while (0)

#pragma unroll 2
  for (int jj = 0; jj < 32; ++jj) {
    const int buf = jj & 1;
    if (jj + 1 < 32) {
      stage_tile(P, Bstage[1 - buf], 2 * jj + 2, wave, lane);
      stage_tile(P, Bstage[1 - buf] + 8192, 2 * jj + 3, wave, lane);
    }
    COMPUTE(&Bstage[buf][0], 2 * jj);
    COMPUTE(&Bstage[buf][8192], 2 * jj + 1);
    __syncthreads();
  }

#undef COMPUTE

  // ---- cross-lane argmin reduce over the 16 code-columns (uint min) ----
#pragma unroll
  for (int i = 0; i < 8; ++i) {
    unsigned D1 = d1[i], D2 = d2[i];
#pragma unroll
    for (int off = 1; off < 16; off <<= 1) {
      unsigned o1 = (unsigned)__shfl_xor((int)D1, off, 64);
      unsigned o2 = (unsigned)__shfl_xor((int)D2, off, 64);
      D2 = min(min(D2, o2), max(D1, o1));
      D1 = min(D1, o1);
    }
    if (c == 0) {
      int lrow = wave * 32 + (i >> 2) * 16 + q * 4 + (i & 3);
      s_k[lrow] = (int)(D1 & 2047u);
      if ((int)((D2 >> 11) - (D1 >> 11)) < EPS_PK) {
        int idx = atomicAdd(&s_nflag, 1);
        s_frows[idx] = lrow;
      }
    }
  }
  __syncthreads();

  // ---- exact fp32 fixup for near-tie rows (round-0 arithmetic, proven) ----
  const int nf = s_nflag;
  for (int f = 0; f < nf; ++f) {
    const int lrow = s_frows[f];
    const float* xr = inp + (size_t)(blockIdx.x * 128 + lrow) * 64;
    float xs[64];
    float x2 = 0.f;
#pragma unroll
    for (int i = 0; i < 16; ++i) {
      float4 v = *(const float4*)(xr + i * 4);
      xs[4 * i + 0] = v.x; xs[4 * i + 1] = v.y; xs[4 * i + 2] = v.z; xs[4 * i + 3] = v.w;
      x2 = fmaf(v.x, v.x, x2); x2 = fmaf(v.y, v.y, x2);
      x2 = fmaf(v.z, v.z, x2); x2 = fmaf(v.w, v.w, x2);
    }
    float dot[8];
#pragma unroll
    for (int cc = 0; cc < 8; ++cc) dot[cc] = 0.f;
    const float* cp = cb + t * 8;
#pragma unroll 4
    for (int d = 0; d < 64; ++d) {
      float xd = xs[d];
#pragma unroll
      for (int cc = 0; cc < 8; ++cc)
        dot[cc] = fmaf(xd, cp[(size_t)d * KCODES + cc], dot[cc]);
    }
    float bd = INFINITY; int bk = 0;
#pragma unroll
    for (int cc = 0; cc < 8; ++cc) {
      float dd = (x2 - 2.0f * dot[cc]) + c2[t * 8 + cc];
      if (dd < bd) { bd = dd; bk = t * 8 + cc; }
    }
    s_rd[t] = bd; s_rk[t] = bk;
    __syncthreads();
    for (int s = 128; s >= 1; s >>= 1) {
      if (t < s) {
        if (s_rd[t + s] < s_rd[t]) { s_rd[t] = s_rd[t + s]; s_rk[t] = s_rk[t + s]; }
      }
      __syncthreads();
    }
    if (t == 0) s_k[lrow] = s_rk[0];
    __syncthreads();
  }

  if (t < 128) atomicAdd(&hist[s_k[t]], 1);

  // ---- epilogue: coalesced float4 STE write + SSE, q gathered from cbT ----
  const float* xb = inp + (size_t)blockIdx.x * (128 * 64);
  float* ob = out + (size_t)blockIdx.x * (128 * 64);
  float serr = 0.f;
#pragma unroll
  for (int i = 0; i < 8; ++i) {
    const int idx = i * 1024 + t * 4;
    const int myk = s_k[idx >> 6];
    const float4 xv = *(const float4*)(xb + idx);
    const float4 qv = *(const float4*)(cbT + (size_t)myk * 64 + (idx & 63));
    float4 ov;
    float e0 = qv.x - xv.x; serr = fmaf(e0, e0, serr); ov.x = xv.x + e0;
    float e1 = qv.y - xv.y; serr = fmaf(e1, e1, serr); ov.y = xv.y + e1;
    float e2 = qv.z - xv.z; serr = fmaf(e2, e2, serr); ov.z = xv.z + e2;
    float e3 = qv.w - xv.w; serr = fmaf(e3, e3, serr); ov.w = xv.w + e3;
    *(float4*)(ob + idx) = ov;
  }
#pragma unroll
  for (int off = 32; off > 0; off >>= 1) serr += __shfl_down(serr, off, 64);
  if (lane == 0) s_red[wave] = serr;
  __syncthreads();
  if (t == 0) atomicAdd(sse, s_red[0] + s_red[1] + s_red[2] + s_red[3]);
}

__global__ void vq_final(const int* __restrict__ hist,
                         const float* __restrict__ sse,
                         float* __restrict__ out) {
  __shared__ float s_red[4];
  const int t = threadIdx.x;
  float s = 0.f;
  for (int k = t; k < KCODES; k += 256) {
    float p = (float)hist[k] * (1.0f / NROWS);
    s += p * logf(p + 1e-10f);
  }
#pragma unroll
  for (int off = 32; off > 0; off >>= 1) s += __shfl_down(s, off, 64);
  if ((t & 63) == 0) s_red[t >> 6] = s;
  __syncthreads();
  if (t == 0) {
    float tot = s_red[0] + s_red[1] + s_red[2] + s_red[3];
    out[NELEM] = expf(-tot);                 // perplexity
    float cl = *sse * (1.0f / NELEM);
    out[NELEM + 1] = cl;                     // codebook_loss
    out[NELEM + 2] = 0.25f * cl;             // commitment_loss
  }
}

extern "C" void kernel_launch(void* const* d_in, const int* in_sizes, int n_in,
                              void* d_out, int out_size, void* d_ws, size_t ws_size,
                              hipStream_t stream) {
  const float* inp = (const float*)d_in[0];
  const float* cb  = (const float*)d_in[1];
  float* out = (float*)d_out;
  char* ws = (char*)d_ws;
  int*   hist = (int*)(ws + WS_HIST);
  float* c2   = (float*)(ws + WS_C2);
  float* c2s  = (float*)(ws + WS_C2S);
  float* sse  = (float*)(ws + WS_SSE);
  char*  P    = ws + WS_P;
  float* cbT  = (float*)(ws + WS_CBT);

  vq_setup<<<KCODES * 8 / 64, 64, 0, stream>>>(cb, c2, c2s, P, cbT, hist, sse);
  vq_main<<<NROWS / 128, 256, 0, stream>>>(inp, cb, c2, c2s, P, cbT, hist, sse, out);
  vq_final<<<1, 256, 0, stream>>>(hist, sse, out);
}